// Round 2
// baseline (1112.249 us; speedup 1.0000x reference)
//
#include <hip/hip_runtime.h>

// MPT attention w/ ALiBi: B=4 S=2048 D=2048 H=16 HD=128, fp32 in/out,
// bf16 MFMA pipeline.
//
// Pipeline:
//   1. transpose_cvt: Wqkv -> WqkvT bf16 [6144][2048], Wout -> WoutT bf16 [2048][2048]
//   2. gemm_qkv: qkv = x @ Wqkv + b ; writes Q,K [B,H,S,HD] bf16, V [B,H,HD,S] bf16 (transposed)
//      A (fp32 x) staged via v_perm pack; B via global_load_lds width=16 (m97 style)
//   3. attn: flash attention, O overwrites Q buffer in place ([B,H,S,HD])
//   4. gemm_out: out = O @ Wout + b_out (fp32 out); BOTH operands via global_load_lds
//
// ws layout (128 MiB): [0) WqkvT 24M ][24M) WoutT 8M ][32M) Q/O 32M ][64M) K 32M ][96M) V^T 32M ]

typedef unsigned short u16;
typedef unsigned int u32;
typedef u16  u16x8 __attribute__((ext_vector_type(8)));
typedef __bf16 bf16x8 __attribute__((ext_vector_type(8)));
typedef float f32x4 __attribute__((ext_vector_type(4)));

__device__ __forceinline__ u16 f2b(float f) {
  union { float f; unsigned u; } v; v.f = f;
  return (u16)((v.u + 0x7fffu + ((v.u >> 16) & 1u)) >> 16);  // RNE
}

// pack two fp32 -> two bf16 (round-half-up: +0x8000, truncate) in one v_perm
__device__ __forceinline__ u32 pk2(float a, float b) {
  u32 ua = __float_as_uint(a) + 0x8000u;
  u32 ub = __float_as_uint(b) + 0x8000u;
  // result bytes[0:1] = ua bytes[2:3] (src1), bytes[2:3] = ub bytes[2:3] (src0, +4)
  return __builtin_amdgcn_perm(ub, ua, 0x07060302u);
}

__device__ __forceinline__ f32x4 mfma16(bf16x8 a, bf16x8 b, f32x4 c) {
  return __builtin_amdgcn_mfma_f32_16x16x32_bf16(a, b, c, 0, 0, 0);
}
__device__ __forceinline__ bf16x8 ldb(const u16* p) { return *(const bf16x8*)p; }

// async global->LDS, 16B per lane; lds dest = wave-uniform base + lane*16
__device__ __forceinline__ void gload16(const u16* g, u16* l) {
  __builtin_amdgcn_global_load_lds(
      (const __attribute__((address_space(1))) u32*)g,
      (__attribute__((address_space(3))) u32*)l, 16, 0, 0);
}

// ---------------------------------------------------------------- transpose+cvt
// src fp32 [R][C] -> dst bf16 [C][R].  R,C multiples of 32. 256 threads, 32x32 tiles.
__global__ __launch_bounds__(256) void transpose_cvt(
    const float* __restrict__ src, u16* __restrict__ dst, int R, int C) {
  __shared__ float tile[32][33];
  const int c0 = blockIdx.x * 32, r0 = blockIdx.y * 32;
  const int tx = threadIdx.x & 31, ty = threadIdx.x >> 5;  // ty 0..7
  #pragma unroll
  for (int i = 0; i < 4; ++i)
    tile[ty + 8 * i][tx] = src[(size_t)(r0 + ty + 8 * i) * C + c0 + tx];
  __syncthreads();
  #pragma unroll
  for (int i = 0; i < 4; ++i)
    dst[(size_t)(c0 + ty + 8 * i) * R + r0 + tx] = f2b(tile[tx][ty + 8 * i]);
}

// ---------------------------------------------------------------- GEMM1: QKV proj
// C[8192,6144] = x[8192,2048] @ Wqkv + b_qkv. 128x128x32 tiles, 4 waves, 4x4 frags.
// A: fp32 loads + pk2 pack -> ds_write_b128 (unpadded [128][32]).
// B: global_load_lds width=16, 2 chunks/wave.
__global__ __launch_bounds__(256) void gemm_qkv(
    const float* __restrict__ x, const u16* __restrict__ wT,
    const float* __restrict__ bias,
    u16* __restrict__ qbuf, u16* __restrict__ kbuf, u16* __restrict__ vbuf) {
  __shared__ u16 smem[128 * 136];  // loop: sA[128*32]+sB[128*32]=8K u16; epilogue: [128][136]
  u16* sA = smem;
  u16* sB = smem + 128 * 32;
  const int tid = threadIdx.x;
  const int lane = tid & 63, wv = tid >> 6;
  const int L = lane & 15, g = lane >> 4;
  const int wm = (wv >> 1) * 64, wn = (wv & 1) * 64;
  const int m0 = blockIdx.y * 128, n0 = blockIdx.x * 128;
  const int row = tid >> 1, sh = tid & 1;

  // B async staging: 8 chunks of 1KB; wave wv handles chunks 2wv, 2wv+1
  const int c0 = wv * 2, c1 = wv * 2 + 1;
  const u16* bp0 = wT + (size_t)(n0 + c0 * 16 + (lane >> 2)) * 2048 + (lane & 3) * 8;
  const u16* bp1 = wT + (size_t)(n0 + c1 * 16 + (lane >> 2)) * 2048 + (lane & 3) * 8;
  u16* lB0 = sB + c0 * 512;
  u16* lB1 = sB + c1 * 512;
  const float* aptr = x + (size_t)(m0 + row) * 2048 + sh * 16;

  f32x4 acc[4][4] = {};

  for (int kt = 0; kt < 64; ++kt) {
    __syncthreads();
    gload16(bp0, lB0);
    gload16(bp1, lB1);
    bp0 += 32; bp1 += 32;
    {
      f32x4 v0 = *(const f32x4*)(aptr + 0);
      f32x4 v1 = *(const f32x4*)(aptr + 4);
      f32x4 v2 = *(const f32x4*)(aptr + 8);
      f32x4 v3 = *(const f32x4*)(aptr + 12);
      aptr += 32;
      uint4 wA0, wA1;
      wA0.x = pk2(v0[0], v0[1]); wA0.y = pk2(v0[2], v0[3]);
      wA0.z = pk2(v1[0], v1[1]); wA0.w = pk2(v1[2], v1[3]);
      wA1.x = pk2(v2[0], v2[1]); wA1.y = pk2(v2[2], v2[3]);
      wA1.z = pk2(v3[0], v3[1]); wA1.w = pk2(v3[2], v3[3]);
      *(uint4*)&sA[row * 32 + sh * 16 + 0] = wA0;
      *(uint4*)&sA[row * 32 + sh * 16 + 8] = wA1;
    }
    __syncthreads();
    bf16x8 af[4], bfr[4];
    #pragma unroll
    for (int t = 0; t < 4; ++t) af[t] = ldb(&sA[(wm + 16 * t + L) * 32 + 8 * g]);
    #pragma unroll
    for (int t = 0; t < 4; ++t) bfr[t] = ldb(&sB[(wn + 16 * t + L) * 32 + 8 * g]);
    #pragma unroll
    for (int ti = 0; ti < 4; ++ti)
      #pragma unroll
      for (int tj = 0; tj < 4; ++tj)
        acc[ti][tj] = mfma16(af[ti], bfr[tj], acc[ti][tj]);
  }

  float bs[4];
  #pragma unroll
  for (int tj = 0; tj < 4; ++tj) bs[tj] = bias[n0 + wn + 16 * tj + L];

  __syncthreads();  // done with sA/sB, reuse whole smem as [128][136] bf16 tile
  #pragma unroll
  for (int ti = 0; ti < 4; ++ti)
    #pragma unroll
    for (int tj = 0; tj < 4; ++tj)
      #pragma unroll
      for (int r = 0; r < 4; ++r)
        smem[(wm + 16 * ti + 4 * g + r) * 136 + wn + 16 * tj + L] =
            f2b(acc[ti][tj][r] + bs[tj]);
  __syncthreads();

  const int bg = m0 >> 11, s0 = m0 & 2047;         // batch, seq base
  const int t3 = n0 >> 11, hh = (n0 & 2047) >> 7;  // 0=q 1=k 2=v; head
  if (t3 < 2) {
    u16* dst = (t3 == 0 ? qbuf : kbuf) + ((size_t)(bg * 16 + hh) * 2048 + s0) * 128;
    #pragma unroll
    for (int mm = 0; mm < 8; ++mm)
      *(u16x8*)&dst[row * 128 + sh * 64 + 8 * mm] =
          *(const u16x8*)&smem[row * 136 + sh * 64 + 8 * mm];
  } else {
    // V transposed: vbuf[(bh*128 + hd)*2048 + s]
    u16* dst = vbuf + (size_t)(bg * 16 + hh) * 128 * 2048 + s0;
    #pragma unroll
    for (int mm = 0; mm < 8; ++mm) {
      u16x8 v;
      #pragma unroll
      for (int jj = 0; jj < 8; ++jj) v[jj] = smem[(sh * 64 + 8 * mm + jj) * 136 + row];
      *(u16x8*)&dst[(size_t)row * 2048 + sh * 64 + 8 * mm] = v;
    }
  }
}

// ---------------------------------------------------------------- flash attention
// Block = (b, h, 64 q-rows); 4 waves x 16 q-rows. k-tiles of 128. Q frags in regs.
// K tile [128][136], V^T tile [128][136] in LDS. P reuses K-tile space.
extern __shared__ u16 dyn_smem[];
__global__ __launch_bounds__(256) void attn(
    const u16* __restrict__ kbuf, const u16* __restrict__ vbuf,
    u16* __restrict__ qobuf) {
  u16* sK = dyn_smem;              // [128][136]
  u16* sV = dyn_smem + 128 * 136;  // [128][136]
  const int tid = threadIdx.x;
  const int lane = tid & 63, wv = tid >> 6;
  const int L = lane & 15, g = lane >> 4;
  const int qt = (int)gridDim.x - 1 - (int)blockIdx.x;  // longest blocks first
  const int h = blockIdx.y, b = blockIdx.z;
  const int q0 = qt * 64 + wv * 16;  // this wave's q base
  const size_t bh = (size_t)(b * 16 + h);
  const int row = tid >> 1, sh = tid & 1;

  const u16* Qp = qobuf + (bh * 2048 + q0) * 128;
  bf16x8 qf[4];
  #pragma unroll
  for (int ks = 0; ks < 4; ++ks) qf[ks] = ldb(&Qp[L * 128 + ks * 32 + 8 * g]);

  const float slope = exp2f(-0.5f * (float)(h + 1));
  const float scale = 0.08838834764831845f;  // 1/sqrt(128)
  float m_[4] = {-1e30f, -1e30f, -1e30f, -1e30f};
  float l_[4] = {0.f, 0.f, 0.f, 0.f};
  f32x4 oa[8] = {};
  u16* sP = sK + wv * 16 * 136;  // per-wave private P slice

  const int jmax = (qt * 64 + 63) >> 7;
  for (int j = 0; j <= jmax; ++j) {
    __syncthreads();
    const u16* Kp = kbuf + (bh * 2048 + (size_t)j * 128) * 128;
    const u16* Vp = vbuf + bh * 128 * 2048 + j * 128;
    #pragma unroll
    for (int mm = 0; mm < 8; ++mm)
      *(u16x8*)&sK[row * 136 + sh * 64 + 8 * mm] =
          *(const u16x8*)&Kp[row * 128 + sh * 64 + 8 * mm];
    #pragma unroll
    for (int mm = 0; mm < 8; ++mm)
      *(u16x8*)&sV[row * 136 + sh * 64 + 8 * mm] =
          *(const u16x8*)&Vp[(size_t)row * 2048 + sh * 64 + 8 * mm];
    __syncthreads();

    // S = Q K^T (16 q-rows x 128 kpos per wave)
    f32x4 sc[8] = {};
    #pragma unroll
    for (int ks = 0; ks < 4; ++ks)
      #pragma unroll
      for (int tc = 0; tc < 8; ++tc) {
        bf16x8 kf = ldb(&sK[(16 * tc + L) * 136 + ks * 32 + 8 * g]);
        sc[tc] = mfma16(qf[ks], kf, sc[tc]);
      }

    // scale + alibi + causal; C-layout: row = 4g+r, col = 16tc+L
    float tmax[4] = {-1e30f, -1e30f, -1e30f, -1e30f};
    const int kbase = j * 128 + L;
    const bool need_mask = (j * 128 + 127) > q0;
    #pragma unroll
    for (int tc = 0; tc < 8; ++tc) {
      const int kpos = kbase + 16 * tc;
      const float ab = slope * (float)(kpos - 2047);
      #pragma unroll
      for (int r = 0; r < 4; ++r) {
        float s = sc[tc][r] * scale + ab;
        if (need_mask && kpos > q0 + 4 * g + r) s = -1e30f;
        sc[tc][r] = s;
        tmax[r] = fmaxf(tmax[r], s);
      }
    }
    #pragma unroll
    for (int r = 0; r < 4; ++r) {
      #pragma unroll
      for (int d = 1; d < 16; d <<= 1)
        tmax[r] = fmaxf(tmax[r], __shfl_xor(tmax[r], d, 64));
    }
    float al[4], ps[4];
    #pragma unroll
    for (int r = 0; r < 4; ++r) {
      float mn = fmaxf(m_[r], tmax[r]);
      al[r] = __expf(m_[r] - mn);
      m_[r] = mn;
      ps[r] = 0.f;
    }
    #pragma unroll
    for (int tc = 0; tc < 8; ++tc)
      #pragma unroll
      for (int r = 0; r < 4; ++r) {
        float p = __expf(sc[tc][r] - m_[r]);
        sc[tc][r] = p;
        ps[r] += p;
      }
    #pragma unroll
    for (int r = 0; r < 4; ++r) {
      #pragma unroll
      for (int d = 1; d < 16; d <<= 1) ps[r] += __shfl_xor(ps[r], d, 64);
      l_[r] = l_[r] * al[r] + ps[r];
    }
    #pragma unroll
    for (int tn = 0; tn < 8; ++tn)
      #pragma unroll
      for (int r = 0; r < 4; ++r) oa[tn][r] *= al[r];

    __syncthreads();  // all waves done reading sK before P overwrites it
    #pragma unroll
    for (int tc = 0; tc < 8; ++tc)
      #pragma unroll
      for (int r = 0; r < 4; ++r)
        sP[(4 * g + r) * 136 + 16 * tc + L] = f2b(sc[tc][r]);

    // O += P V
    #pragma unroll
    for (int ks = 0; ks < 4; ++ks) {
      bf16x8 pf = ldb(&sP[L * 136 + ks * 32 + 8 * g]);
      #pragma unroll
      for (int tn = 0; tn < 8; ++tn) {
        bf16x8 vf = ldb(&sV[(16 * tn + L) * 136 + ks * 32 + 8 * g]);
        oa[tn] = mfma16(pf, vf, oa[tn]);
      }
    }
  }

  // epilogue: O/l -> bf16, overwrite own Q rows
  u16* Op = qobuf + (bh * 2048 + q0) * 128;
  float inv[4];
  #pragma unroll
  for (int r = 0; r < 4; ++r) inv[r] = 1.0f / l_[r];
  #pragma unroll
  for (int tn = 0; tn < 8; ++tn)
    #pragma unroll
    for (int r = 0; r < 4; ++r)
      Op[(4 * g + r) * 128 + 16 * tn + L] = f2b(oa[tn][r] * inv[r]);
}

// ---------------------------------------------------------------- GEMM2: out proj
// out[8192,2048] = O @ Wout + b_out.  Both operands bf16 -> global_load_lds staging.
__global__ __launch_bounds__(256) void gemm_out(
    const u16* __restrict__ obuf, const u16* __restrict__ wT,
    const float* __restrict__ bias, float* __restrict__ out) {
  __shared__ u16 smem[128 * 64];  // sA[128*32] + sB[128*32]
  u16* sA = smem;
  u16* sB = smem + 128 * 32;
  const int tid = threadIdx.x;
  const int lane = tid & 63, wv = tid >> 6;
  const int L = lane & 15, g = lane >> 4;
  const int wm = (wv >> 1) * 64, wn = (wv & 1) * 64;
  const int m0 = blockIdx.y * 128, n0 = blockIdx.x * 128;
  const int bg = m0 >> 11, s0 = m0 & 2047;

  const int c0 = wv * 2, c1 = wv * 2 + 1;
  const int lrow = lane >> 2, lcol = (lane & 3) * 8;
  const u16* bp0 = wT + (size_t)(n0 + c0 * 16 + lrow) * 2048 + lcol;
  const u16* bp1 = wT + (size_t)(n0 + c1 * 16 + lrow) * 2048 + lcol;
  u16* lB0 = sB + c0 * 512;
  u16* lB1 = sB + c1 * 512;
  u16* lA0 = sA + c0 * 512;
  u16* lA1 = sA + c1 * 512;

  f32x4 acc[4][4] = {};

  for (int hH = 0; hH < 16; ++hH) {
    const u16* ap0 = obuf + ((size_t)(bg * 16 + hH) * 2048 + s0 + c0 * 16 + lrow) * 128 + lcol;
    const u16* ap1 = obuf + ((size_t)(bg * 16 + hH) * 2048 + s0 + c1 * 16 + lrow) * 128 + lcol;
    #pragma unroll
    for (int kq = 0; kq < 4; ++kq) {
      __syncthreads();
      gload16(ap0 + kq * 32, lA0);
      gload16(ap1 + kq * 32, lA1);
      gload16(bp0, lB0);
      gload16(bp1, lB1);
      bp0 += 32; bp1 += 32;
      __syncthreads();
      bf16x8 af[4], bfr[4];
      #pragma unroll
      for (int t = 0; t < 4; ++t) af[t] = ldb(&sA[(wm + 16 * t + L) * 32 + 8 * g]);
      #pragma unroll
      for (int t = 0; t < 4; ++t) bfr[t] = ldb(&sB[(wn + 16 * t + L) * 32 + 8 * g]);
      #pragma unroll
      for (int ti = 0; ti < 4; ++ti)
        #pragma unroll
        for (int tj = 0; tj < 4; ++tj)
          acc[ti][tj] = mfma16(af[ti], bfr[tj], acc[ti][tj]);
    }
  }

  float bs[4];
  #pragma unroll
  for (int tj = 0; tj < 4; ++tj) bs[tj] = bias[n0 + wn + 16 * tj + L];
  #pragma unroll
  for (int ti = 0; ti < 4; ++ti)
    #pragma unroll
    for (int tj = 0; tj < 4; ++tj)
      #pragma unroll
      for (int r = 0; r < 4; ++r)
        out[(size_t)(m0 + wm + 16 * ti + 4 * g + r) * 2048 + n0 + wn + 16 * tj + L] =
            acc[ti][tj][r] + bs[tj];
}

// ---------------------------------------------------------------- launch
extern "C" void kernel_launch(void* const* d_in, const int* in_sizes, int n_in,
                              void* d_out, int out_size, void* d_ws, size_t ws_size,
                              hipStream_t stream) {
  const float* x    = (const float*)d_in[0];
  const float* Wqkv = (const float*)d_in[1];
  const float* bqkv = (const float*)d_in[2];
  const float* Wout = (const float*)d_in[3];
  const float* bout = (const float*)d_in[4];
  float* out = (float*)d_out;

  char* ws = (char*)d_ws;
  u16* wqkvT = (u16*)(ws + 0);           // 6144*2048*2  = 25165824
  u16* woutT = (u16*)(ws + 25165824);    // 2048*2048*2  =  8388608
  u16* qbuf  = (u16*)(ws + 33554432);    // 4*16*2048*128*2 = 33554432 (becomes O)
  u16* kbuf  = (u16*)(ws + 67108864);
  u16* vbuf  = (u16*)(ws + 100663296);   // transposed [B,H,HD,S]; total 128 MiB

  transpose_cvt<<<dim3(192, 64), 256, 0, stream>>>(Wqkv, wqkvT, 2048, 6144);
  transpose_cvt<<<dim3(64, 64), 256, 0, stream>>>(Wout, woutT, 2048, 2048);
  gemm_qkv<<<dim3(48, 64), 256, 0, stream>>>(x, wqkvT, bqkv, qbuf, kbuf, vbuf);
  attn<<<dim3(32, 16, 4), 256, 69632, stream>>>(kbuf, vbuf, qbuf);
  gemm_out<<<dim3(16, 64), 256, 0, stream>>>(qbuf, woutT, bout, out);
}

// Round 3
// 1012.759 us; speedup vs baseline: 1.0982x; 1.0982x over previous
//
#include <hip/hip_runtime.h>

// MPT attention w/ ALiBi: B=4 S=2048 D=2048 H=16 HD=128, fp32 in/out,
// bf16 MFMA pipeline.
//
// Pipeline:
//   1. transpose_cvt: Wqkv -> WqkvT bf16 [6144][2048], Wout -> WoutT bf16 [2048][2048]
//   2. gemm_qkv: qkv = x @ Wqkv + b ; 128x256 tiles, explicit reg double-buffer
//      staging (VGPR->LDS), pk2 fp32->bf16 pack. Writes Q,K [B,H,S,HD], V^T [B,H,HD,S].
//   3. attn: flash attention, O overwrites Q buffer in place
//   4. gemm_out: out = O @ Wout + b_out; 128x128, reg double-buffer staging
//
// ws layout (128 MiB): [0) WqkvT 24M ][24M) WoutT 8M ][32M) Q/O 32M ][64M) K 32M ][96M) V^T 32M ]

typedef unsigned short u16;
typedef unsigned int u32;
typedef u16  u16x8 __attribute__((ext_vector_type(8)));
typedef __bf16 bf16x8 __attribute__((ext_vector_type(8)));
typedef float f32x4 __attribute__((ext_vector_type(4)));

__device__ __forceinline__ u16 f2b(float f) {
  union { float f; unsigned u; } v; v.f = f;
  return (u16)((v.u + 0x7fffu + ((v.u >> 16) & 1u)) >> 16);  // RNE
}

// pack two fp32 -> two bf16 (round-half-up) in one v_perm
__device__ __forceinline__ u32 pk2(float a, float b) {
  u32 ua = __float_as_uint(a) + 0x8000u;
  u32 ub = __float_as_uint(b) + 0x8000u;
  return __builtin_amdgcn_perm(ub, ua, 0x07060302u);  // [ua_hi16 | ub_hi16]
}

__device__ __forceinline__ f32x4 mfma16(bf16x8 a, bf16x8 b, f32x4 c) {
  return __builtin_amdgcn_mfma_f32_16x16x32_bf16(a, b, c, 0, 0, 0);
}
__device__ __forceinline__ bf16x8 ldb(const u16* p) { return *(const bf16x8*)p; }

// ---------------------------------------------------------------- transpose+cvt
__global__ __launch_bounds__(256) void transpose_cvt(
    const float* __restrict__ src, u16* __restrict__ dst, int R, int C) {
  __shared__ float tile[32][33];
  const int c0 = blockIdx.x * 32, r0 = blockIdx.y * 32;
  const int tx = threadIdx.x & 31, ty = threadIdx.x >> 5;
  #pragma unroll
  for (int i = 0; i < 4; ++i)
    tile[ty + 8 * i][tx] = src[(size_t)(r0 + ty + 8 * i) * C + c0 + tx];
  __syncthreads();
  #pragma unroll
  for (int i = 0; i < 4; ++i)
    dst[(size_t)(c0 + ty + 8 * i) * R + r0 + tx] = f2b(tile[tx][ty + 8 * i]);
}

// ---------------------------------------------------------------- GEMM1: QKV proj
// C[8192,6144] = x @ Wqkv + b. 128x256x32 tiles, 4 waves (2m x 2n), 4x8 frags/wave.
// Explicit register double-buffer: load kt+1 during compute of kt.
__global__ __launch_bounds__(256, 2) void gemm_qkv(
    const float* __restrict__ x, const u16* __restrict__ wT,
    const float* __restrict__ bias,
    u16* __restrict__ qbuf, u16* __restrict__ kbuf, u16* __restrict__ vbuf) {
  __shared__ u16 smem[128 * 136];   // loop: sA[128*32] + sB[256*32] = 24KB; epi: [128][136]
  u16* sA = smem;
  u16* sB = smem + 128 * 32;
  const int tid = threadIdx.x;
  const int lane = tid & 63, wv = tid >> 6;
  const int L = lane & 15, g = lane >> 4;
  const int wm = (wv >> 1) * 64, wn = (wv & 1) * 128;
  const int m0 = blockIdx.y * 128, n0 = blockIdx.x * 256;
  const int row = tid >> 1, sh = tid & 1;

  const float* aptr = x + (size_t)(m0 + row) * 2048 + sh * 16;
  const u16*  bptr = wT + (size_t)(n0 + tid) * 2048;

  // prologue: load tile kt=0 into regs
  f32x4 ar0 = *(const f32x4*)(aptr + 0);
  f32x4 ar1 = *(const f32x4*)(aptr + 4);
  f32x4 ar2 = *(const f32x4*)(aptr + 8);
  f32x4 ar3 = *(const f32x4*)(aptr + 12);
  uint4 br0 = *(const uint4*)(bptr + 0);
  uint4 br1 = *(const uint4*)(bptr + 8);
  uint4 br2 = *(const uint4*)(bptr + 16);
  uint4 br3 = *(const uint4*)(bptr + 24);
  aptr += 32; bptr += 32;

  f32x4 acc[4][8] = {};

  for (int kt = 0; kt < 64; ++kt) {
    __syncthreads();  // prior compute's LDS reads complete
    {
      uint4 wA0, wA1;
      wA0.x = pk2(ar0[0], ar0[1]); wA0.y = pk2(ar0[2], ar0[3]);
      wA0.z = pk2(ar1[0], ar1[1]); wA0.w = pk2(ar1[2], ar1[3]);
      wA1.x = pk2(ar2[0], ar2[1]); wA1.y = pk2(ar2[2], ar2[3]);
      wA1.z = pk2(ar3[0], ar3[1]); wA1.w = pk2(ar3[2], ar3[3]);
      *(uint4*)&sA[row * 32 + sh * 16 + 0] = wA0;
      *(uint4*)&sA[row * 32 + sh * 16 + 8] = wA1;
      *(uint4*)&sB[tid * 32 + 0]  = br0;
      *(uint4*)&sB[tid * 32 + 8]  = br1;
      *(uint4*)&sB[tid * 32 + 16] = br2;
      *(uint4*)&sB[tid * 32 + 24] = br3;
    }
    __syncthreads();
    if (kt < 63) {  // prefetch kt+1 during compute
      ar0 = *(const f32x4*)(aptr + 0);
      ar1 = *(const f32x4*)(aptr + 4);
      ar2 = *(const f32x4*)(aptr + 8);
      ar3 = *(const f32x4*)(aptr + 12);
      br0 = *(const uint4*)(bptr + 0);
      br1 = *(const uint4*)(bptr + 8);
      br2 = *(const uint4*)(bptr + 16);
      br3 = *(const uint4*)(bptr + 24);
      aptr += 32; bptr += 32;
    }
    bf16x8 af[4], bfr[8];
    #pragma unroll
    for (int t = 0; t < 4; ++t) af[t] = ldb(&sA[(wm + 16 * t + L) * 32 + 8 * g]);
    #pragma unroll
    for (int t = 0; t < 8; ++t) bfr[t] = ldb(&sB[(wn + 16 * t + L) * 32 + 8 * g]);
    #pragma unroll
    for (int ti = 0; ti < 4; ++ti)
      #pragma unroll
      for (int tj = 0; tj < 8; ++tj)
        acc[ti][tj] = mfma16(af[ti], bfr[tj], acc[ti][tj]);
  }

  float bs[8];
  #pragma unroll
  for (int tj = 0; tj < 8; ++tj) bs[tj] = bias[n0 + wn + 16 * tj + L];

  const int bg = m0 >> 11, s0 = m0 & 2047;
  // two 128-col epilogue phases through [128][136] LDS
  #pragma unroll
  for (int p = 0; p < 2; ++p) {
    __syncthreads();
    if ((wv & 1) == p) {
      #pragma unroll
      for (int ti = 0; ti < 4; ++ti)
        #pragma unroll
        for (int tj = 0; tj < 8; ++tj)
          #pragma unroll
          for (int r = 0; r < 4; ++r)
            smem[(wm + 16 * ti + 4 * g + r) * 136 + 16 * tj + L] =
                f2b(acc[ti][tj][r] + bs[tj]);
    }
    __syncthreads();
    const int nb = n0 + p * 128;
    const int t3 = nb >> 11, hh = (nb & 2047) >> 7;
    if (t3 < 2) {
      u16* dst = (t3 == 0 ? qbuf : kbuf) + ((size_t)(bg * 16 + hh) * 2048 + s0) * 128;
      #pragma unroll
      for (int mm = 0; mm < 8; ++mm)
        *(u16x8*)&dst[row * 128 + sh * 64 + 8 * mm] =
            *(const u16x8*)&smem[row * 136 + sh * 64 + 8 * mm];
    } else {
      u16* dst = vbuf + (size_t)(bg * 16 + hh) * 128 * 2048 + s0;
      #pragma unroll
      for (int mm = 0; mm < 8; ++mm) {
        u16x8 v;
        #pragma unroll
        for (int jj = 0; jj < 8; ++jj) v[jj] = smem[(sh * 64 + 8 * mm + jj) * 136 + row];
        *(u16x8*)&dst[(size_t)row * 2048 + sh * 64 + 8 * mm] = v;
      }
    }
  }
}

// ---------------------------------------------------------------- flash attention
extern __shared__ u16 dyn_smem[];
__global__ __launch_bounds__(256) void attn(
    const u16* __restrict__ kbuf, const u16* __restrict__ vbuf,
    u16* __restrict__ qobuf) {
  u16* sK = dyn_smem;              // [128][136]
  u16* sV = dyn_smem + 128 * 136;  // [128][136]
  const int tid = threadIdx.x;
  const int lane = tid & 63, wv = tid >> 6;
  const int L = lane & 15, g = lane >> 4;
  const int qt = (int)gridDim.x - 1 - (int)blockIdx.x;
  const int h = blockIdx.y, b = blockIdx.z;
  const int q0 = qt * 64 + wv * 16;
  const size_t bh = (size_t)(b * 16 + h);
  const int row = tid >> 1, sh = tid & 1;

  const u16* Qp = qobuf + (bh * 2048 + q0) * 128;
  bf16x8 qf[4];
  #pragma unroll
  for (int ks = 0; ks < 4; ++ks) qf[ks] = ldb(&Qp[L * 128 + ks * 32 + 8 * g]);

  const float slope = exp2f(-0.5f * (float)(h + 1));
  const float scale = 0.08838834764831845f;
  float m_[4] = {-1e30f, -1e30f, -1e30f, -1e30f};
  float l_[4] = {0.f, 0.f, 0.f, 0.f};
  f32x4 oa[8] = {};
  u16* sP = sK + wv * 16 * 136;

  const int jmax = (qt * 64 + 63) >> 7;
  for (int j = 0; j <= jmax; ++j) {
    __syncthreads();
    const u16* Kp = kbuf + (bh * 2048 + (size_t)j * 128) * 128;
    const u16* Vp = vbuf + bh * 128 * 2048 + j * 128;
    #pragma unroll
    for (int mm = 0; mm < 8; ++mm)
      *(u16x8*)&sK[row * 136 + sh * 64 + 8 * mm] =
          *(const u16x8*)&Kp[row * 128 + sh * 64 + 8 * mm];
    #pragma unroll
    for (int mm = 0; mm < 8; ++mm)
      *(u16x8*)&sV[row * 136 + sh * 64 + 8 * mm] =
          *(const u16x8*)&Vp[(size_t)row * 2048 + sh * 64 + 8 * mm];
    __syncthreads();

    f32x4 sc[8] = {};
    #pragma unroll
    for (int ks = 0; ks < 4; ++ks)
      #pragma unroll
      for (int tc = 0; tc < 8; ++tc) {
        bf16x8 kf = ldb(&sK[(16 * tc + L) * 136 + ks * 32 + 8 * g]);
        sc[tc] = mfma16(qf[ks], kf, sc[tc]);
      }

    float tmax[4] = {-1e30f, -1e30f, -1e30f, -1e30f};
    const int kbase = j * 128 + L;
    const bool need_mask = (j * 128 + 127) > q0;
    #pragma unroll
    for (int tc = 0; tc < 8; ++tc) {
      const int kpos = kbase + 16 * tc;
      const float ab = slope * (float)(kpos - 2047);
      #pragma unroll
      for (int r = 0; r < 4; ++r) {
        float s = sc[tc][r] * scale + ab;
        if (need_mask && kpos > q0 + 4 * g + r) s = -1e30f;
        sc[tc][r] = s;
        tmax[r] = fmaxf(tmax[r], s);
      }
    }
    #pragma unroll
    for (int r = 0; r < 4; ++r) {
      #pragma unroll
      for (int d = 1; d < 16; d <<= 1)
        tmax[r] = fmaxf(tmax[r], __shfl_xor(tmax[r], d, 64));
    }
    float al[4], ps[4];
    #pragma unroll
    for (int r = 0; r < 4; ++r) {
      float mn = fmaxf(m_[r], tmax[r]);
      al[r] = __expf(m_[r] - mn);
      m_[r] = mn;
      ps[r] = 0.f;
    }
    #pragma unroll
    for (int tc = 0; tc < 8; ++tc)
      #pragma unroll
      for (int r = 0; r < 4; ++r) {
        float p = __expf(sc[tc][r] - m_[r]);
        sc[tc][r] = p;
        ps[r] += p;
      }
    #pragma unroll
    for (int r = 0; r < 4; ++r) {
      #pragma unroll
      for (int d = 1; d < 16; d <<= 1) ps[r] += __shfl_xor(ps[r], d, 64);
      l_[r] = l_[r] * al[r] + ps[r];
    }
    #pragma unroll
    for (int tn = 0; tn < 8; ++tn)
      #pragma unroll
      for (int r = 0; r < 4; ++r) oa[tn][r] *= al[r];

    __syncthreads();
    #pragma unroll
    for (int tc = 0; tc < 8; ++tc)
      #pragma unroll
      for (int r = 0; r < 4; ++r)
        sP[(4 * g + r) * 136 + 16 * tc + L] = f2b(sc[tc][r]);

    #pragma unroll
    for (int ks = 0; ks < 4; ++ks) {
      bf16x8 pf = ldb(&sP[L * 136 + ks * 32 + 8 * g]);
      #pragma unroll
      for (int tn = 0; tn < 8; ++tn) {
        bf16x8 vf = ldb(&sV[(16 * tn + L) * 136 + ks * 32 + 8 * g]);
        oa[tn] = mfma16(pf, vf, oa[tn]);
      }
    }
  }

  u16* Op = qobuf + (bh * 2048 + q0) * 128;
  float inv[4];
  #pragma unroll
  for (int r = 0; r < 4; ++r) inv[r] = 1.0f / l_[r];
  #pragma unroll
  for (int tn = 0; tn < 8; ++tn)
    #pragma unroll
    for (int r = 0; r < 4; ++r)
      Op[(4 * g + r) * 128 + 16 * tn + L] = f2b(oa[tn][r] * inv[r]);
}

// ---------------------------------------------------------------- GEMM2: out proj
// out[8192,2048] = O @ Wout + b_out. 128x128x32 tiles, reg double-buffer staging.
__global__ __launch_bounds__(256) void gemm_out(
    const u16* __restrict__ obuf, const u16* __restrict__ wT,
    const float* __restrict__ bias, float* __restrict__ out) {
  __shared__ u16 smem[128 * 64];  // sA[128*32] + sB[128*32]
  u16* sA = smem;
  u16* sB = smem + 128 * 32;
  const int tid = threadIdx.x;
  const int lane = tid & 63, wv = tid >> 6;
  const int L = lane & 15, g = lane >> 4;
  const int wm = (wv >> 1) * 64, wn = (wv & 1) * 64;
  const int m0 = blockIdx.y * 128, n0 = blockIdx.x * 128;
  const int row = tid >> 1, sh = tid & 1;
  const int bg = m0 >> 11, s0 = m0 & 2047;

  // A: O in [B,H,S,HD]; k = kt*32 + sh*16 -> head kt>>2, col (kt&3)*32 + sh*16
  const u16* abase = obuf + ((size_t)(bg * 16) * 2048 + s0 + row) * 128 + sh * 16;
  const u16* bptr = wT + (size_t)(n0 + row) * 2048 + sh * 16;

  uint4 a0 = *(const uint4*)(abase + 0);
  uint4 a1 = *(const uint4*)(abase + 8);
  uint4 b0 = *(const uint4*)(bptr + 0);
  uint4 b1 = *(const uint4*)(bptr + 8);
  bptr += 32;

  f32x4 acc[4][4] = {};

  for (int kt = 0; kt < 64; ++kt) {
    __syncthreads();
    *(uint4*)&sA[row * 32 + sh * 16 + 0] = a0;
    *(uint4*)&sA[row * 32 + sh * 16 + 8] = a1;
    *(uint4*)&sB[row * 32 + sh * 16 + 0] = b0;
    *(uint4*)&sB[row * 32 + sh * 16 + 8] = b1;
    __syncthreads();
    if (kt < 63) {
      const int k = (kt + 1) * 32;
      const u16* ap = abase + (size_t)(k >> 7) * 2048 * 128 + (k & 127);
      a0 = *(const uint4*)(ap + 0);
      a1 = *(const uint4*)(ap + 8);
      b0 = *(const uint4*)(bptr + 0);
      b1 = *(const uint4*)(bptr + 8);
      bptr += 32;
    }
    bf16x8 af[4], bfr[4];
    #pragma unroll
    for (int t = 0; t < 4; ++t) af[t] = ldb(&sA[(wm + 16 * t + L) * 32 + 8 * g]);
    #pragma unroll
    for (int t = 0; t < 4; ++t) bfr[t] = ldb(&sB[(wn + 16 * t + L) * 32 + 8 * g]);
    #pragma unroll
    for (int ti = 0; ti < 4; ++ti)
      #pragma unroll
      for (int tj = 0; tj < 4; ++tj)
        acc[ti][tj] = mfma16(af[ti], bfr[tj], acc[ti][tj]);
  }

  float bs[4];
  #pragma unroll
  for (int tj = 0; tj < 4; ++tj) bs[tj] = bias[n0 + wn + 16 * tj + L];
  #pragma unroll
  for (int ti = 0; ti < 4; ++ti)
    #pragma unroll
    for (int tj = 0; tj < 4; ++tj)
      #pragma unroll
      for (int r = 0; r < 4; ++r)
        out[(size_t)(m0 + wm + 16 * ti + 4 * g + r) * 2048 + n0 + wn + 16 * tj + L] =
            acc[ti][tj][r] + bs[tj];
}

// ---------------------------------------------------------------- launch
extern "C" void kernel_launch(void* const* d_in, const int* in_sizes, int n_in,
                              void* d_out, int out_size, void* d_ws, size_t ws_size,
                              hipStream_t stream) {
  const float* x    = (const float*)d_in[0];
  const float* Wqkv = (const float*)d_in[1];
  const float* bqkv = (const float*)d_in[2];
  const float* Wout = (const float*)d_in[3];
  const float* bout = (const float*)d_in[4];
  float* out = (float*)d_out;

  char* ws = (char*)d_ws;
  u16* wqkvT = (u16*)(ws + 0);           // 6144*2048*2  = 25165824
  u16* woutT = (u16*)(ws + 25165824);    // 2048*2048*2  =  8388608
  u16* qbuf  = (u16*)(ws + 33554432);    // 4*16*2048*128*2 = 33554432 (becomes O)
  u16* kbuf  = (u16*)(ws + 67108864);
  u16* vbuf  = (u16*)(ws + 100663296);   // transposed [B,H,HD,S]; total 128 MiB

  transpose_cvt<<<dim3(192, 64), 256, 0, stream>>>(Wqkv, wqkvT, 2048, 6144);
  transpose_cvt<<<dim3(64, 64), 256, 0, stream>>>(Wout, woutT, 2048, 2048);
  gemm_qkv<<<dim3(24, 64), 256, 0, stream>>>(x, wqkvT, bqkv, qbuf, kbuf, vbuf);
  attn<<<dim3(32, 16, 4), 256, 69632, stream>>>(kbuf, vbuf, qbuf);
  gemm_out<<<dim3(16, 64), 256, 0, stream>>>(qbuf, woutT, bout, out);
}